// Round 1
// baseline (1887.297 us; speedup 1.0000x reference)
//
#include <hip/hip_runtime.h>

typedef _Float16 f16;
typedef _Float16 f16x8 __attribute__((ext_vector_type(8)));
typedef _Float16 f16x4 __attribute__((ext_vector_type(4)));
typedef float    f32x4 __attribute__((ext_vector_type(4)));

#define GLOAD_LDS16(g, s) __builtin_amdgcn_global_load_lds( \
    (__attribute__((address_space(1))) void*)(g),           \
    (__attribute__((address_space(3))) void*)(s), 16, 0, 0)

// C[M,N] = A[M,K] @ B[N,K]^T (+bias).  fp16 in, fp32 acc.
// 256x256 tile, BK=64, 8 waves (2M x 4N), double-buffered 128KB dynamic LDS.
// Schedule: per K-tile, 4 phases {ds_read subtile; barrier; setprio+16 MFMA; barrier};
// next tile's 8 global_load_lds issued at phase 0, single vmcnt(0)+barrier at tile
// boundary (loads in flight across 8 barriers = full-tile slack).
// LDS XOR-swizzle: LDS[row][slot] = G[row][slot ^ (row&7)] (16B slots), staged via
// pre-swizzled GLOBAL source (linear LDS dest, rule 21), read with same XOR.
// Row remap on C: crow = gm + radd + rskip*(gm/rdiv)  (KV-cache concat placement).
__global__ __launch_bounds__(512, 2) void gemm_nt256(
    const f16* __restrict__ A, int lda, long long Abat,
    const f16* __restrict__ B, int ldb, long long Bbat,
    float* Cf, int ldcf, long long Cfbat,
    f16* Ch, int ldch, long long Chbat,
    const float* __restrict__ bias,
    int K, int rdiv, int rskip, int radd)
{
    extern __shared__ f16 smem[];
    f16* As = smem;              // [2][256*64]
    f16* Bs = smem + 32768;      // [2][256*64]

    const int bz = blockIdx.z;
    A += (long long)bz * Abat;
    B += (long long)bz * Bbat;
    if (Cf) Cf += (long long)bz * Cfbat;
    if (Ch) Ch += (long long)bz * Chbat;

    const int tid = threadIdx.x;
    const int l = tid & 63, w = tid >> 6;

    // T1: XCD-aware block swizzle (all launches have nwg % 8 == 0)
    const int nbx = gridDim.x;
    const int nwg = nbx * gridDim.y;
    const int lin = blockIdx.y * nbx + blockIdx.x;
    const int id = (lin & 7) * (nwg >> 3) + (lin >> 3);
    const int tile_n = (id % nbx) << 8;
    const int tile_m = (id / nbx) << 8;

    const int wm = (w >> 2) << 7;   // 0 / 128
    const int wn = (w & 3) << 6;    // 0 / 64 / 128 / 192

    const f16* Ag = A + (long long)tile_m * lda;
    const f16* Bg = B + (long long)tile_n * ldb;

    const int lr16 = l & 15, lhi = l >> 4, llo8 = l & 7, lrr = l >> 3;
    // staging: lane l of wave w covers row (w*8 + l>>3) of each 64-row block,
    // 16B slot (l&7); global source column pre-swizzled by ^(row&7) = ^(l>>3).
    const f16* aStage = Ag + (long long)(w * 8 + lrr) * lda + ((llo8 ^ lrr) << 3);
    const f16* bStage = Bg + (long long)(w * 8 + lrr) * ldb + ((llo8 ^ lrr) << 3);
    const int stLds = w * 512;      // (w*8 rows) * 64 elems

    f32x4 acc[8][4] = {};

    auto stage = [&](int dst, int k0) {
        const f16* ag = aStage + k0;
        const f16* bg = bStage + k0;
        f16* ad = As + dst * 16384 + stLds;
        f16* bd = Bs + dst * 16384 + stLds;
        #pragma unroll
        for (int j = 0; j < 4; ++j) {
            GLOAD_LDS16(ag + (long long)j * 64 * lda, ad + j * 4096);
            GLOAD_LDS16(bg + (long long)j * 64 * ldb, bd + j * 4096);
        }
    };

    const int NT = K >> 6;

    stage(0, 0);
    asm volatile("s_waitcnt vmcnt(0)" ::: "memory");
    __builtin_amdgcn_s_barrier();

    for (int kt = 0; kt < NT; ++kt) {
        const int cur = kt & 1;
        const f16* Ab = As + cur * 16384;
        const f16* Bb = Bs + cur * 16384;
        f16x8 bf[4][2];
        #pragma unroll
        for (int p = 0; p < 4; ++p) {
            f16x8 af[2][2];
            #pragma unroll
            for (int i = 0; i < 2; ++i) {
                const int row = wm + (2 * p + i) * 16 + lr16;
                #pragma unroll
                for (int kk = 0; kk < 2; ++kk)
                    af[i][kk] = *(const f16x8*)&Ab[row * 64 + (((kk * 4 + lhi) ^ llo8) << 3)];
            }
            if (p == 0) {
                #pragma unroll
                for (int nf = 0; nf < 4; ++nf) {
                    const int row = wn + nf * 16 + lr16;
                    #pragma unroll
                    for (int kk = 0; kk < 2; ++kk)
                        bf[nf][kk] = *(const f16x8*)&Bb[row * 64 + (((kk * 4 + lhi) ^ llo8) << 3)];
                }
                if (kt + 1 < NT) stage(cur ^ 1, (kt + 1) << 6);
            }
            __builtin_amdgcn_s_barrier();
            __builtin_amdgcn_s_setprio(1);
            #pragma unroll
            for (int i = 0; i < 2; ++i)
                #pragma unroll
                for (int nf = 0; nf < 4; ++nf)
                    #pragma unroll
                    for (int kk = 0; kk < 2; ++kk)
                        acc[2 * p + i][nf] = __builtin_amdgcn_mfma_f32_16x16x32_f16(
                            af[i][kk], bf[nf][kk], acc[2 * p + i][nf], 0, 0, 0);
            __builtin_amdgcn_s_setprio(0);
            __builtin_amdgcn_s_barrier();
        }
        // tile boundary: the ONLY vmcnt drain; next tile's loads had ~3 phases in flight
        asm volatile("s_waitcnt vmcnt(0)" ::: "memory");
        __builtin_amdgcn_s_barrier();
    }

    const int lrow4 = lhi << 2, lcol = lr16;
    #pragma unroll
    for (int nf = 0; nf < 4; ++nf) {
        const int gn = tile_n + wn + nf * 16 + lcol;
        const float bb = bias ? bias[gn] : 0.f;
        #pragma unroll
        for (int mf = 0; mf < 8; ++mf) {
            #pragma unroll
            for (int r = 0; r < 4; ++r) {
                const int gm = tile_m + wm + mf * 16 + lrow4 + r;
                const int crow = gm + radd + rskip * (gm / rdiv);
                const float v = acc[mf][nf][r] + bb;
                if (Cf) Cf[(long long)crow * ldcf + gn] = v;
                if (Ch) Ch[(long long)crow * ldch + gn] = (f16)v;
            }
        }
    }
}

// straight fp32 -> fp16, 4 elements/thread
__global__ void k_f32_to_f16(const float* __restrict__ in, f16* __restrict__ out, long long n4)
{
    long long i = (long long)blockIdx.x * 256 + threadIdx.x;
    if (i >= n4) return;
    float4 v = ((const float4*)in)[i];
    f16x4 h = { (f16)v.x, (f16)v.y, (f16)v.z, (f16)v.w };
    ((f16x4*)out)[i] = h;
}

// KV-cache copy: src [4][2048][2048] -> dst rows b*4096 + t (fp32, optionally fp16)
__global__ void k_cache_copy(const float* __restrict__ src, float* __restrict__ dstf,
                             f16* __restrict__ dsth)
{
    long long i4 = (long long)blockIdx.x * 256 + threadIdx.x;
    long long i = i4 * 4;
    if (i >= 16777216LL) return;
    int b = (int)(i >> 22);                    // 2048*2048 = 2^22
    long long o = i + ((long long)b << 22);    // -> b*2^23 + rem  (dst batch stride 4096*2048)
    float4 v = ((const float4*)src)[i4];
    *(float4*)(dstf + o) = v;
    if (dsth) {
        f16x4 h = { (f16)v.x, (f16)v.y, (f16)v.z, (f16)v.w };
        *(f16x4*)(dsth + o) = h;
    }
}

// in [R][C] fp32 -> out [C][R] fp16 (batched via z)
__global__ void k_transpose_f32_f16(const float* __restrict__ in, f16* __restrict__ out,
                                    int R, int C, long long inbat, long long outbat)
{
    __shared__ float t[64][65];
    in += (long long)blockIdx.z * inbat;
    out += (long long)blockIdx.z * outbat;
    const int r0 = blockIdx.y * 64, c0 = blockIdx.x * 64;
    const int tx = threadIdx.x & 63, ty = threadIdx.x >> 6;
    #pragma unroll
    for (int i = 0; i < 64; i += 4)
        t[ty + i][tx] = in[(long long)(r0 + ty + i) * C + (c0 + tx)];
    __syncthreads();
    #pragma unroll
    for (int i = 0; i < 64; i += 4)
        out[(long long)(c0 + ty + i) * R + (r0 + tx)] = (f16)t[tx][ty + i];
}

// column softmax (over q axis) of scores[b][2048][4096] fp32 -> attn fp16
// block: 256 threads = 8 q-groups x 32 cols; grid (4096/32, 1, B)
__global__ void k_softmax_q(const float* __restrict__ sc, f16* __restrict__ attn)
{
    const long long boff = (long long)blockIdx.z * 2048 * 4096;
    const float* Sb = sc + boff;
    f16* Ab = attn + boff;
    const int lc = threadIdx.x & 31;
    const int qg = threadIdx.x >> 5;
    const int col = blockIdx.x * 32 + lc;

    float m = -3.0e38f, s = 0.f;
    for (int q = qg; q < 2048; q += 8) {
        float x = Sb[(long long)q * 4096 + col];
        if (x > m) { s = s * __expf(m - x) + 1.f; m = x; }
        else         s += __expf(x - m);
    }
    __shared__ float ms[8][32], ss[8][32], Mf[32], If[32];
    ms[qg][lc] = m; ss[qg][lc] = s;
    __syncthreads();
    if (threadIdx.x < 32) {
        float M = ms[0][lc];
        #pragma unroll
        for (int i = 1; i < 8; i++) M = fmaxf(M, ms[i][lc]);
        float tt = 0.f;
        #pragma unroll
        for (int i = 0; i < 8; i++) tt += ss[i][lc] * __expf(ms[i][lc] - M);
        Mf[lc] = M; If[lc] = 1.f / tt;
    }
    __syncthreads();
    const float M = Mf[lc], inv = If[lc];
    for (int q = qg; q < 2048; q += 8) {
        float x = Sb[(long long)q * 4096 + col];
        Ab[(long long)q * 4096 + col] = (f16)(__expf(x - M) * inv);
    }
}

extern "C" void kernel_launch(void* const* d_in, const int* in_sizes, int n_in,
                              void* d_out, int out_size, void* d_ws, size_t ws_size,
                              hipStream_t stream)
{
    const float* x    = (const float*)d_in[0];
    const float* kc   = (const float*)d_in[1];
    const float* vc   = (const float*)d_in[2];
    const float* Wq   = (const float*)d_in[3];
    const float* bq   = (const float*)d_in[4];
    const float* Wk   = (const float*)d_in[5];
    const float* bk   = (const float*)d_in[6];
    const float* Wv   = (const float*)d_in[7];
    const float* bv   = (const float*)d_in[8];
    const float* Wff  = (const float*)d_in[9];
    const float* bff  = (const float*)d_in[10];
    const float* Wout = (const float*)d_in[11];
    const float* bout = (const float*)d_in[12];

    float* out   = (float*)d_out;          // [8192][2048]
    float* out_k = out + 16777216LL;       // [4][4096][2048]
    float* out_v = out_k + 33554432LL;     // [4][4096][2048]

    char* p = (char*)d_ws;
    auto alloc = [&](size_t bytes) { char* r = p; p += (bytes + 255) & ~255ULL; return r; };
    f16* xh     = (f16*)alloc(33554432);     // [8192][2048]
    f16* qh     = (f16*)alloc(33554432);     // [8192][2048]  (contiguous with xh)
    f16* kh     = (f16*)alloc(67108864);     // [4][4096][2048]
    f16* vth    = (f16*)alloc(67108864);     // [4][2048][4096]  (v transposed)
    f16* wqt    = (f16*)alloc(8388608);      // [2048][2048]
    f16* wkt    = (f16*)alloc(8388608);
    f16* wvt    = (f16*)alloc(8388608);
    f16* wfft   = (f16*)alloc(33554432);     // [8192][2048]  (Wff^T)
    f16* woutt  = (f16*)alloc(33554432);     // [2048][8192]  (Wout^T)
    f16* ctxh   = (f16*)alloc(33554432);     // [8192][2048]
    float* scores = (float*)alloc(134217728);// [4][2048][4096]
    f16* hh     = (f16*)scores;              // [8192][8192] — reuses scores (dead by then)
    f16* attnh  = (f16*)xh;                  // [4][2048][4096] — reuses xh+qh (dead by then)
    (void)ws_size; (void)in_sizes; (void)n_in; (void)out_size;

    const int NOREMAP = 1 << 30;
    const int SMEM = 131072;

    static int smem_set = 0;
    if (!smem_set) {
        hipFuncSetAttribute((const void*)gemm_nt256,
                            hipFuncAttributeMaxDynamicSharedMemorySize, SMEM);
        smem_set = 1;
    }

    // 1. x -> fp16
    k_f32_to_f16<<<16384, 256, 0, stream>>>(x, xh, 4194304LL);
    // 2. weights -> fp16, transposed to [N][K]
    k_transpose_f32_f16<<<dim3(32, 32, 1),  256, 0, stream>>>(Wq,   wqt,   2048, 2048, 0, 0);
    k_transpose_f32_f16<<<dim3(32, 32, 1),  256, 0, stream>>>(Wk,   wkt,   2048, 2048, 0, 0);
    k_transpose_f32_f16<<<dim3(32, 32, 1),  256, 0, stream>>>(Wv,   wvt,   2048, 2048, 0, 0);
    k_transpose_f32_f16<<<dim3(128, 32, 1), 256, 0, stream>>>(Wff,  wfft,  2048, 8192, 0, 0);
    k_transpose_f32_f16<<<dim3(32, 128, 1), 256, 0, stream>>>(Wout, woutt, 8192, 2048, 0, 0);
    // 3. cache copies: fp32 into d_out concat positions; k also fp16 into kh rows [b][0..2047]
    k_cache_copy<<<16384, 256, 0, stream>>>(kc, out_k, kh);
    k_cache_copy<<<16384, 256, 0, stream>>>(vc, out_v, nullptr);

    // 4-6. projections (M=8192, N=2048, K=2048)
    dim3 gproj(8, 32, 1);
    // q: fp16 only
    gemm_nt256<<<gproj, 512, SMEM, stream>>>(xh, 2048, 0, wqt, 2048, 0,
        nullptr, 0, 0, qh, 2048, 0, bq, 2048, NOREMAP, 0, 0);
    // k: fp32 -> d_out (concat rows), fp16 -> kh (concat rows)
    gemm_nt256<<<gproj, 512, SMEM, stream>>>(xh, 2048, 0, wkt, 2048, 0,
        out_k, 2048, 0, kh, 2048, 0, bk, 2048, 2048, 2048, 2048);
    // v: fp32 -> d_out (concat rows) only
    gemm_nt256<<<gproj, 512, SMEM, stream>>>(xh, 2048, 0, wvt, 2048, 0,
        out_v, 2048, 0, nullptr, 0, 0, bv, 2048, 2048, 2048, 2048);

    // 7. v (full concat, from d_out) -> fp16 transposed [b][2048][4096]
    k_transpose_f32_f16<<<dim3(32, 64, 4), 256, 0, stream>>>(out_v, vth, 4096, 2048,
                                                             8388608LL, 8388608LL);

    // 8. scores[b] = q[b] @ k[b]^T   (M=2048, N=4096, K=2048, fp32 out)
    gemm_nt256<<<dim3(16, 8, 4), 512, SMEM, stream>>>(qh, 2048, 4194304LL, kh, 2048, 8388608LL,
        scores, 4096, 8388608LL, nullptr, 0, 0, nullptr, 2048, NOREMAP, 0, 0);

    // 9. softmax over q (axis=1), fp16 attn
    k_softmax_q<<<dim3(128, 1, 4), 256, 0, stream>>>(scores, attnh);

    // 10. ctx[b] = attn[b] @ vth[b]^T  (M=2048, N=2048, K=4096, fp16 out)
    gemm_nt256<<<dim3(8, 8, 4), 512, SMEM, stream>>>(attnh, 4096, 8388608LL, vth, 4096, 8388608LL,
        nullptr, 0, 0, ctxh, 2048, 4194304LL, nullptr, 4096, NOREMAP, 0, 0);

    // 11. h = ctx @ Wff + bff  (M=8192, N=8192, K=2048, fp16 out)
    gemm_nt256<<<dim3(32, 32, 1), 512, SMEM, stream>>>(ctxh, 2048, 0, wfft, 2048, 0,
        nullptr, 0, 0, hh, 8192, 0, bff, 2048, NOREMAP, 0, 0);

    // 12. out = h @ Wout + bout  (M=8192, N=2048, K=8192, fp32 out)
    gemm_nt256<<<dim3(8, 32, 1), 512, SMEM, stream>>>(hh, 8192, 0, woutt, 8192, 0,
        out, 2048, 0, nullptr, 0, 0, bout, 8192, NOREMAP, 0, 0);
}